// Round 2
// baseline (225.103 us; speedup 1.0000x reference)
//
#include <hip/hip_runtime.h>
#include <hip/hip_bf16.h>
#include <stdint.h>

#define L1DIM 1536
#define NOUT  144           // 128 (W1) + 16 (Wf) layer-1 outputs
#define MTILE 32            // rows per block
#define KHALF 24            // K=32 steps per K-half (768 k per half)

typedef __bf16 bf16;
typedef __bf16 bf16x8 __attribute__((ext_vector_type(8)));
typedef float  floatx4 __attribute__((ext_vector_type(4)));

// ---------------------------------------------------------------------------
// Prep: pack [W1;Wf] (144 x 1536 fp32) into bf16 in MFMA-B-fragment order:
//   pw[(k/8)*144 + n][j], j=0..7   (16 B per (k-octet, n) pair)
// Coalesced reads: t = n*192 + o, so consecutive lanes read consecutive
// k-octets of one weight row (contiguous 2 KB per wave). Writes are the
// scattered side of the transpose (16 B each, L2-absorbed, 442 KB total).
// ---------------------------------------------------------------------------
__global__ void pack_weights(const float* __restrict__ W1,
                             const float* __restrict__ Wf,
                             bf16* __restrict__ pw) {
    int t = blockIdx.x * blockDim.x + threadIdx.x;   // 0 .. 144*192-1
    if (t >= NOUT * 192) return;
    int n = t / 192;         // output feature 0..143
    int o = t % 192;         // k-octet 0..191
    const float* src = (n < 128) ? (W1 + (size_t)n * L1DIM + o * 8)
                                 : (Wf + (size_t)(n - 128) * L1DIM + o * 8);
    float4 s0 = ((const float4*)src)[0];
    float4 s1 = ((const float4*)src)[1];
    bf16x8 v;
    v[0] = (bf16)s0.x; v[1] = (bf16)s0.y; v[2] = (bf16)s0.z; v[3] = (bf16)s0.w;
    v[4] = (bf16)s1.x; v[5] = (bf16)s1.y; v[6] = (bf16)s1.z; v[7] = (bf16)s1.w;
    *(bf16x8*)(pw + ((size_t)o * NOUT + n) * 8) = v;
}

// ---------------------------------------------------------------------------
// Fused kernel, barrier-free K-loop. Block: 256 threads = 4 waves
//   wave = (row-group ms in {0,1}) x (K-half kh in {0,1})
// Each wave: 16 rows x all 144 outputs x 768 K, B fragments loaded directly
// from L2-resident pw (no LDS staging, no __syncthreads in the K-loop).
// Partial sums from the two K-halves combined through ep[] in the epilogue.
// ---------------------------------------------------------------------------
__global__ __launch_bounds__(256) void layerstacks_main(
    const float* __restrict__ x, const int* __restrict__ lsidx,
    const bf16* __restrict__ pw,
    const float* __restrict__ b1, const float* __restrict__ bf_,
    const float* __restrict__ W2, const float* __restrict__ b2,
    const float* __restrict__ Wo, const float* __restrict__ bo,
    float* __restrict__ out)
{
    __shared__ float ep[MTILE][148];       // layer-1 results, padded

    const int tid  = threadIdx.x;
    const int wv   = tid >> 6;
    const int ln   = tid & 63;
    const int quad = ln >> 4;
    const int lm   = ln & 15;

    const int R0 = blockIdx.x * MTILE;
    const int ms = wv & 1;                  // row group
    const int kh = wv >> 1;                 // K half

    const float* xrow = x + (size_t)(R0 + ms * 16 + lm) * L1DIM + kh * (KHALF * 32);
    // B fragment base for this lane: k-octet (kh*96 + quad), feature lm
    const bf16* pwb = pw + ((size_t)(kh * 96 + quad) * NOUT + lm) * 8;

    floatx4 acc[9];
#pragma unroll
    for (int i = 0; i < 9; i++) acc[i] = (floatx4){0.f, 0.f, 0.f, 0.f};

#pragma unroll 3
    for (int s = 0; s < KHALF; s++) {
        // A fragment: row (lane&15), k = s*32 + quad*8 .. +8  (32 B from x)
        float4 a0 = *(const float4*)(xrow + s * 32 + quad * 8);
        float4 a1 = *(const float4*)(xrow + s * 32 + quad * 8 + 4);
        bf16x8 af;
        af[0] = (bf16)a0.x; af[1] = (bf16)a0.y; af[2] = (bf16)a0.z; af[3] = (bf16)a0.w;
        af[4] = (bf16)a1.x; af[5] = (bf16)a1.y; af[6] = (bf16)a1.z; af[7] = (bf16)a1.w;

        const bf16* bb = pwb + (size_t)s * 4 * NOUT * 8;   // advance 4 k-octets
#pragma unroll
        for (int nt = 0; nt < 9; nt++) {
            bf16x8 bfrag = *(const bf16x8*)(bb + nt * 16 * 8);
            acc[nt] = __builtin_amdgcn_mfma_f32_16x16x32_bf16(af, bfrag, acc[nt], 0, 0, 0);
        }
    }

    // ---- combine K-halves through LDS (C layout: row=quad*4+r, col=lm) ----
    if (kh == 0) {
#pragma unroll
        for (int nt = 0; nt < 9; nt++)
#pragma unroll
            for (int r = 0; r < 4; r++)
                ep[ms * 16 + quad * 4 + r][nt * 16 + lm] = acc[nt][r];
    }
    __syncthreads();
    if (kh == 1) {
#pragma unroll
        for (int nt = 0; nt < 9; nt++)
#pragma unroll
            for (int r = 0; r < 4; r++)
                ep[ms * 16 + quad * 4 + r][nt * 16 + lm] += acc[nt][r];
    }
    __syncthreads();

    // ---- epilogue: 8 threads per row ----
    const int er   = tid >> 3;          // row in tile, 0..31
    const int sub  = tid & 7;           // output-group, 0..7
    const int grow = R0 + er;
    const int bkt  = lsidx[grow];

    const float l1c15 = ep[er][bkt * 16 + 15] + b1[bkt * 16 + 15];
    const float l1f15 = ep[er][128 + 15] + bf_[15];

    float l1x[30];
#pragma unroll
    for (int j = 0; j < 15; j++) {
        float tj = (ep[er][bkt * 16 + j] + b1[bkt * 16 + j])
                 + (ep[er][128 + j]      + bf_[j]);
        float sq = tj * tj * (127.0f / 128.0f);
        l1x[j]      = fminf(fmaxf(sq, 0.f), 1.f);
        l1x[15 + j] = fminf(fmaxf(tj, 0.f), 1.f);
    }

    float part = 0.f;
#pragma unroll
    for (int o = 0; o < 8; o++) {
        const int oi = bkt * 64 + sub * 8 + o;
        const float2* wrow = (const float2*)(W2 + oi * 30);   // 8B-aligned
        float a = b2[oi];
#pragma unroll
        for (int j2 = 0; j2 < 15; j2++) {
            float2 w = wrow[j2];
            a += l1x[2 * j2] * w.x + l1x[2 * j2 + 1] * w.y;
        }
        a = fminf(fmaxf(a, 0.f), 1.f);
        part += a * Wo[oi];
    }
    part += __shfl_xor(part, 1);
    part += __shfl_xor(part, 2);
    part += __shfl_xor(part, 4);
    if (sub == 0) out[grow] = part + bo[bkt] + l1c15 + l1f15;
}

extern "C" void kernel_launch(void* const* d_in, const int* in_sizes, int n_in,
                              void* d_out, int out_size, void* d_ws, size_t ws_size,
                              hipStream_t stream) {
    const float* x   = (const float*)d_in[0];
    const int*   idx = (const int*)  d_in[1];
    const float* W1  = (const float*)d_in[2];
    const float* b1  = (const float*)d_in[3];
    const float* Wf  = (const float*)d_in[4];
    const float* bf  = (const float*)d_in[5];
    const float* W2  = (const float*)d_in[6];
    const float* b2  = (const float*)d_in[7];
    const float* Wo  = (const float*)d_in[8];
    const float* bo  = (const float*)d_in[9];
    float* out = (float*)d_out;
    bf16*  pw  = (bf16*)d_ws;                 // 442368 B of workspace

    pack_weights<<<dim3((NOUT * 192 + 255) / 256), dim3(256), 0, stream>>>(W1, Wf, pw);
    layerstacks_main<<<dim3(16384 / MTILE), dim3(256), 0, stream>>>(
        x, idx, pw, b1, bf, W2, b2, Wo, bo, out);
}

// Round 3
// 183.693 us; speedup vs baseline: 1.2254x; 1.2254x over previous
//
#include <hip/hip_runtime.h>
#include <hip/hip_bf16.h>
#include <stdint.h>

#define L1DIM 1536
#define NOUT  144           // 128 (W1) + 16 (Wf) layer-1 outputs
#define MTILE 64            // rows per block
#define BK    64            // K per staged slab
#define NITER (L1DIM / BK)  // 24
#define NCHUNK16 1152       // (BK/8)*NOUT 16B-chunks per slab (18432 B)

typedef __bf16 bf16;
typedef __bf16 bf16x8 __attribute__((ext_vector_type(8)));
typedef float  floatx4 __attribute__((ext_vector_type(4)));

// ---------------------------------------------------------------------------
// Prep: pack [W1;Wf] (144 x 1536 fp32) into bf16 in MFMA-B-fragment order:
//   pw[(k/8)*144 + n][j], j=0..7   (16 B per (k-octet, n) pair)
// Coalesced reads: consecutive lanes read consecutive 32 B chunks of one row.
// ---------------------------------------------------------------------------
__global__ void pack_weights(const float* __restrict__ W1,
                             const float* __restrict__ Wf,
                             bf16* __restrict__ pw) {
    int t = blockIdx.x * blockDim.x + threadIdx.x;   // 0 .. 144*192-1
    if (t >= NOUT * 192) return;
    int n = t / 192;         // output feature 0..143
    int o = t % 192;         // k-octet 0..191
    const float* src = (n < 128) ? (W1 + (size_t)n * L1DIM + o * 8)
                                 : (Wf + (size_t)(n - 128) * L1DIM + o * 8);
    float4 s0 = ((const float4*)src)[0];
    float4 s1 = ((const float4*)src)[1];
    bf16x8 v;
    v[0] = (bf16)s0.x; v[1] = (bf16)s0.y; v[2] = (bf16)s0.z; v[3] = (bf16)s0.w;
    v[4] = (bf16)s1.x; v[5] = (bf16)s1.y; v[6] = (bf16)s1.z; v[7] = (bf16)s1.w;
    *(bf16x8*)(pw + ((size_t)o * NOUT + n) * 8) = v;
}

__device__ __forceinline__ void gload_lds16(const void* g, void* l) {
    __builtin_amdgcn_global_load_lds(
        (const __attribute__((address_space(1))) void*)g,
        (__attribute__((address_space(3))) void*)l, 16, 0, 0);
}

// ---------------------------------------------------------------------------
// Fused kernel. 512 threads = 8 waves: wave = (row-group rg 0..3) x (n-half).
// Double-buffered B staging: slab ki+1 issued async BEFORE computing slab ki;
// the single end-of-iter barrier drains loads that overlapped full compute.
// A prefetched one iteration ahead in registers.
// ---------------------------------------------------------------------------
__global__ __launch_bounds__(512) void layerstacks_main(
    const float* __restrict__ x, const int* __restrict__ lsidx,
    const bf16* __restrict__ pw,
    const float* __restrict__ b1, const float* __restrict__ bf_,
    const float* __restrict__ W2, const float* __restrict__ b2,
    const float* __restrict__ Wo, const float* __restrict__ bo,
    float* __restrict__ out)
{
    __shared__ bf16  lb[2][8 * NOUT * 8];  // 2 x 18432 B slabs
    __shared__ float ep[MTILE][148];       // layer-1 results, padded

    const int tid  = threadIdx.x;
    const int wv   = tid >> 6;
    const int ln   = tid & 63;
    const int quad = ln >> 4;
    const int lm   = ln & 15;

    const int R0  = blockIdx.x * MTILE;
    const int rg  = wv & 3;                 // row group (16 rows)
    const int nh  = wv >> 2;                // N half
    const int nt0 = nh ? 5 : 0;
    const int ntn = nh ? 4 : 5;

    const float* xrow = x + (size_t)(R0 + rg * 16 + lm) * L1DIM;

    floatx4 acc[5];
#pragma unroll
    for (int i = 0; i < 5; i++) acc[i] = (floatx4){0.f, 0.f, 0.f, 0.f};

    // ---- prologue: stage slab 0, load A for iter 0 ----
#pragma unroll
    for (int c = 0; c < 3; c++) {
        int ch = tid + c * 512;
        if (ch < NCHUNK16) gload_lds16(pw + (size_t)ch * 8, &lb[0][(size_t)ch * 8]);
    }
    float4 a0 = *(const float4*)(xrow + quad * 8);
    float4 a1 = *(const float4*)(xrow + quad * 8 + 4);
    float4 a2 = *(const float4*)(xrow + 32 + quad * 8);
    float4 a3 = *(const float4*)(xrow + 32 + quad * 8 + 4);
    __syncthreads();

    for (int ki = 0; ki < NITER; ki++) {
        const int cur = ki & 1;
        // ---- issue async staging of NEXT slab (overlaps this iter's compute) ----
        if (ki < NITER - 1) {
            const bf16* src = pw + (size_t)(ki + 1) * 8 * NOUT * 8;
#pragma unroll
            for (int c = 0; c < 3; c++) {
                int ch = tid + c * 512;
                if (ch < NCHUNK16) gload_lds16(src + (size_t)ch * 8, &lb[cur ^ 1][(size_t)ch * 8]);
            }
        }
        // ---- cvt current A regs to bf16 fragments ----
        bf16x8 af0, af1;
        af0[0] = (bf16)a0.x; af0[1] = (bf16)a0.y; af0[2] = (bf16)a0.z; af0[3] = (bf16)a0.w;
        af0[4] = (bf16)a1.x; af0[5] = (bf16)a1.y; af0[6] = (bf16)a1.z; af0[7] = (bf16)a1.w;
        af1[0] = (bf16)a2.x; af1[1] = (bf16)a2.y; af1[2] = (bf16)a2.z; af1[3] = (bf16)a2.w;
        af1[4] = (bf16)a3.x; af1[5] = (bf16)a3.y; af1[6] = (bf16)a3.z; af1[7] = (bf16)a3.w;
        // ---- prefetch A for next iter ----
        if (ki < NITER - 1) {
            const float* xk = xrow + (ki + 1) * BK;
            a0 = *(const float4*)(xk + quad * 8);
            a1 = *(const float4*)(xk + quad * 8 + 4);
            a2 = *(const float4*)(xk + 32 + quad * 8);
            a3 = *(const float4*)(xk + 32 + quad * 8 + 4);
        }
        // ---- MFMAs on current slab ----
#pragma unroll
        for (int t = 0; t < 5; t++) {
            if (t < ntn) {
                const int nt = nt0 + t;
                bf16x8 bf0 = *(const bf16x8*)&lb[cur][((quad)     * NOUT + nt * 16 + lm) * 8];
                bf16x8 bf1 = *(const bf16x8*)&lb[cur][((4 + quad) * NOUT + nt * 16 + lm) * 8];
                acc[t] = __builtin_amdgcn_mfma_f32_16x16x32_bf16(af0, bf0, acc[t], 0, 0, 0);
                acc[t] = __builtin_amdgcn_mfma_f32_16x16x32_bf16(af1, bf1, acc[t], 0, 0, 0);
            }
        }
        __syncthreads();   // next-slab staging complete; lb[cur] free to overwrite
    }

    // ---- write layer-1 results to LDS (C layout: row=quad*4+r, col=lm) ----
#pragma unroll
    for (int t = 0; t < 5; t++) {
        if (t < ntn) {
            const int nt = nt0 + t;
#pragma unroll
            for (int r = 0; r < 4; r++)
                ep[rg * 16 + quad * 4 + r][nt * 16 + lm] = acc[t][r];
        }
    }
    __syncthreads();

    // ---- epilogue: 8 threads per row, 64 rows = 512 threads ----
    const int er   = tid >> 3;          // row in tile, 0..63
    const int sub  = tid & 7;           // output-group, 0..7
    const int grow = R0 + er;
    const int bkt  = lsidx[grow];

    const float l1c15 = ep[er][bkt * 16 + 15] + b1[bkt * 16 + 15];
    const float l1f15 = ep[er][128 + 15] + bf_[15];

    float l1x[30];
#pragma unroll
    for (int j = 0; j < 15; j++) {
        float tj = (ep[er][bkt * 16 + j] + b1[bkt * 16 + j])
                 + (ep[er][128 + j]      + bf_[j]);
        float sq = tj * tj * (127.0f / 128.0f);
        l1x[j]      = fminf(fmaxf(sq, 0.f), 1.f);
        l1x[15 + j] = fminf(fmaxf(tj, 0.f), 1.f);
    }

    float part = 0.f;
#pragma unroll
    for (int o = 0; o < 8; o++) {
        const int oi = bkt * 64 + sub * 8 + o;
        const float2* wrow = (const float2*)(W2 + oi * 30);   // 8B-aligned
        float a = b2[oi];
#pragma unroll
        for (int j2 = 0; j2 < 15; j2++) {
            float2 w = wrow[j2];
            a += l1x[2 * j2] * w.x + l1x[2 * j2 + 1] * w.y;
        }
        a = fminf(fmaxf(a, 0.f), 1.f);
        part += a * Wo[oi];
    }
    part += __shfl_xor(part, 1);
    part += __shfl_xor(part, 2);
    part += __shfl_xor(part, 4);
    if (sub == 0) out[grow] = part + bo[bkt] + l1c15 + l1f15;
}

extern "C" void kernel_launch(void* const* d_in, const int* in_sizes, int n_in,
                              void* d_out, int out_size, void* d_ws, size_t ws_size,
                              hipStream_t stream) {
    const float* x   = (const float*)d_in[0];
    const int*   idx = (const int*)  d_in[1];
    const float* W1  = (const float*)d_in[2];
    const float* b1  = (const float*)d_in[3];
    const float* Wf  = (const float*)d_in[4];
    const float* bf  = (const float*)d_in[5];
    const float* W2  = (const float*)d_in[6];
    const float* b2  = (const float*)d_in[7];
    const float* Wo  = (const float*)d_in[8];
    const float* bo  = (const float*)d_in[9];
    float* out = (float*)d_out;
    bf16*  pw  = (bf16*)d_ws;                 // 442368 B of workspace

    pack_weights<<<dim3((NOUT * 192 + 255) / 256), dim3(256), 0, stream>>>(W1, Wf, pw);
    layerstacks_main<<<dim3(16384 / MTILE), dim3(512), 0, stream>>>(
        x, idx, pw, b1, bf, W2, b2, Wo, bo, out);
}

// Round 4
// 183.137 us; speedup vs baseline: 1.2291x; 1.0030x over previous
//
#include <hip/hip_runtime.h>
#include <hip/hip_bf16.h>
#include <stdint.h>

#define L1DIM  1536
#define NOUT   144          // 128 (W1) + 16 (Wf) layer-1 outputs
#define NSPLIT 3            // K splits (B-third = 144*512*2B = 147456 B LDS)
#define KSPL   512          // K per split
#define KSTEPS 16           // K=32 MFMA steps per split
#define ROWS   16384
#define RT     16           // rows per tile
#define NRT    1024         // row tiles
#define BLKS   85           // blocks per split (grid = 255)
#define TPB    13           // row tiles per block (85*13=1105 >= 1024)
#define PCOLS  32           // partial cols kept per row (bucket 16 + shared 16)

typedef __bf16 bf16;
typedef __bf16 bf16x8 __attribute__((ext_vector_type(8)));
typedef float  floatx4 __attribute__((ext_vector_type(4)));

// ---------------------------------------------------------------------------
// Pack [W1;Wf] (144 x 1536 fp32) -> bf16 in B-fragment order, grouped by
// K-third so each third is one contiguous 147456 B LDS image:
//   pw[(third*64 + o_local)*144 + n][0..7],  o = k/8 (k-octet), o_local = o%64
// ---------------------------------------------------------------------------
__global__ void pack_weights(const float* __restrict__ W1,
                             const float* __restrict__ Wf,
                             bf16* __restrict__ pw) {
    int t = blockIdx.x * blockDim.x + threadIdx.x;   // 0 .. 144*192-1
    if (t >= NOUT * 192) return;
    int n = t / 192;         // output feature 0..143
    int o = t % 192;         // k-octet 0..191  (consecutive per lane -> coalesced reads)
    const float* src = (n < 128) ? (W1 + (size_t)n * L1DIM + o * 8)
                                 : (Wf + (size_t)(n - 128) * L1DIM + o * 8);
    float4 s0 = ((const float4*)src)[0];
    float4 s1 = ((const float4*)src)[1];
    bf16x8 v;
    v[0] = (bf16)s0.x; v[1] = (bf16)s0.y; v[2] = (bf16)s0.z; v[3] = (bf16)s0.w;
    v[4] = (bf16)s1.x; v[5] = (bf16)s1.y; v[6] = (bf16)s1.z; v[7] = (bf16)s1.w;
    int third = o >> 6, ol = o & 63;
    *(bf16x8*)(pw + (((size_t)third * 64 + ol) * NOUT + n) * 8) = v;
}

__device__ __forceinline__ void gload_lds16(const void* g, void* l) {
    __builtin_amdgcn_global_load_lds(
        (const __attribute__((address_space(1))) void*)g,
        (__attribute__((address_space(3))) void*)l, 16, 0, 0);
}

__device__ __forceinline__ bf16x8 cvt8(float4 a, float4 b) {
    bf16x8 r;
    r[0] = (bf16)a.x; r[1] = (bf16)a.y; r[2] = (bf16)a.z; r[3] = (bf16)a.w;
    r[4] = (bf16)b.x; r[5] = (bf16)b.y; r[6] = (bf16)b.z; r[7] = (bf16)b.w;
    return r;
}

// ---------------------------------------------------------------------------
// K-split layer-1 GEMM: grid = 3 splits x 85 blocks, 512 threads (8 waves).
// Block stages its B-third into LDS ONCE (single barrier), then every wave
// free-runs a barrier-free K-loop over two independent 16-row tiles that
// share the B ds_reads. Bucket-gathered partials (32 cols/row) -> pt.
// ---------------------------------------------------------------------------
__global__ __launch_bounds__(512) void gemm_l1(
    const float* __restrict__ x, const int* __restrict__ lsidx,
    const bf16* __restrict__ pw, float* __restrict__ pt)
{
    __shared__ bf16 lb[64 * NOUT * 8];   // 147456 B: one K-third of B

    const int tid  = threadIdx.x;
    const int wv   = tid >> 6;
    const int ln   = tid & 63;
    const int quad = ln >> 4;
    const int lm   = ln & 15;

    const int q   = blockIdx.x / BLKS;   // K-split id 0..2
    const int blk = blockIdx.x % BLKS;

    // ---- stage B-third (one barrier in the whole kernel) ----
    {
        const bf16* src = pw + (size_t)q * 64 * NOUT * 8;
        for (int c = tid; c < 64 * NOUT; c += 512)
            gload_lds16(src + (size_t)c * 8, &lb[(size_t)c * 8]);
    }
    __syncthreads();

    // ---- unit assignment: wave handles tiles tA and (optionally) tB ----
    const int tA = blk * TPB + wv;            // wv in 0..7, TPB=13
    const int tB = blk * TPB + 8 + wv;
    const bool vA = (tA < NRT);
    if (!vA) return;                           // no barriers after this point
    const bool vB = (8 + wv < TPB) && (tB < NRT);
    const int rA = tA * RT;
    const int rB = vB ? tB * RT : rA;          // clamp: harmless duplicate loads

    const float* xa = x + (size_t)(rA + lm) * L1DIM + q * KSPL;
    const float* xb = x + (size_t)(rB + lm) * L1DIM + q * KSPL;

    floatx4 accA[9], accB[9];
#pragma unroll
    for (int i = 0; i < 9; i++) {
        accA[i] = (floatx4){0.f, 0.f, 0.f, 0.f};
        accB[i] = (floatx4){0.f, 0.f, 0.f, 0.f};
    }

    // ---- barrier-free K loop, A prefetched one step ahead ----
    float4 pa0 = *(const float4*)(xa + quad * 8);
    float4 pa1 = *(const float4*)(xa + quad * 8 + 4);
    float4 pb0 = *(const float4*)(xb + quad * 8);
    float4 pb1 = *(const float4*)(xb + quad * 8 + 4);

    for (int s = 0; s < KSTEPS; s++) {
        bf16x8 afA = cvt8(pa0, pa1);
        bf16x8 afB = cvt8(pb0, pb1);
        if (s < KSTEPS - 1) {
            const float* na = xa + (s + 1) * 32 + quad * 8;
            pa0 = *(const float4*)na;
            pa1 = *(const float4*)(na + 4);
            const float* nb = xb + (s + 1) * 32 + quad * 8;
            pb0 = *(const float4*)nb;
            pb1 = *(const float4*)(nb + 4);
        }
        const bf16* lbase = &lb[((size_t)(s * 4 + quad) * NOUT) * 8];
#pragma unroll
        for (int t = 0; t < 9; t++) {
            bf16x8 bfrag = *(const bf16x8*)&lbase[(t * 16 + lm) * 8];
            accA[t] = __builtin_amdgcn_mfma_f32_16x16x32_bf16(afA, bfrag, accA[t], 0, 0, 0);
            accB[t] = __builtin_amdgcn_mfma_f32_16x16x32_bf16(afB, bfrag, accB[t], 0, 0, 0);
        }
    }

    // ---- bucket-gather & store partials: pt[q][row][0..15]=bucket, [16..31]=shared ----
#pragma unroll
    for (int u = 0; u < 2; u++) {
        const floatx4* acc = u ? accB : accA;
        const int r0 = u ? rB : rA;
        if (u && !vB) break;
#pragma unroll
        for (int rp = 0; rp < 4; rp++) {
            const int row = r0 + quad * 4 + rp;
            const int bkt = lsidx[row];
            float c = acc[0][rp];
#pragma unroll
            for (int t = 1; t < 8; t++) c = (bkt == t) ? acc[t][rp] : c;
            const float f = acc[8][rp];
            float* dst = pt + ((size_t)q * ROWS + row) * PCOLS;
            dst[lm]      = c;
            dst[16 + lm] = f;
        }
    }
}

// ---------------------------------------------------------------------------
// Epilogue: sum the 3 K-split partials, add biases, layers 2+3.
// 256 threads = 32 rows x 8 threads.
// ---------------------------------------------------------------------------
__global__ __launch_bounds__(256) void epilogue(
    const float* __restrict__ pt, const int* __restrict__ lsidx,
    const float* __restrict__ b1, const float* __restrict__ bf_,
    const float* __restrict__ W2, const float* __restrict__ b2,
    const float* __restrict__ Wo, const float* __restrict__ bo,
    float* __restrict__ out)
{
    __shared__ float ep[32][33];

    const int tid = threadIdx.x;
    const int er  = tid >> 3;           // row in block, 0..31
    const int sub = tid & 7;            // 0..7
    const int row = blockIdx.x * 32 + er;

    // cooperative load: thread sums its float4 across the 3 splits
    float4 s = {0.f, 0.f, 0.f, 0.f};
#pragma unroll
    for (int q = 0; q < NSPLIT; q++) {
        float4 v = *(const float4*)&pt[((size_t)q * ROWS + row) * PCOLS + sub * 4];
        s.x += v.x; s.y += v.y; s.z += v.z; s.w += v.w;
    }
    *(float4*)&ep[er][sub * 4] = s;
    __syncthreads();

    const int bkt = lsidx[row];
    const float l1c15 = ep[er][15] + b1[bkt * 16 + 15];
    const float l1f15 = ep[er][31] + bf_[15];

    float l1x[30];
#pragma unroll
    for (int j = 0; j < 15; j++) {
        float tj = (ep[er][j] + b1[bkt * 16 + j]) + (ep[er][16 + j] + bf_[j]);
        float sq = tj * tj * (127.0f / 128.0f);
        l1x[j]      = fminf(fmaxf(sq, 0.f), 1.f);
        l1x[15 + j] = fminf(fmaxf(tj, 0.f), 1.f);
    }

    float part = 0.f;
#pragma unroll
    for (int o = 0; o < 8; o++) {
        const int oi = bkt * 64 + sub * 8 + o;
        const float2* wrow = (const float2*)(W2 + oi * 30);   // 8B-aligned
        float a = b2[oi];
#pragma unroll
        for (int j2 = 0; j2 < 15; j2++) {
            float2 w = wrow[j2];
            a += l1x[2 * j2] * w.x + l1x[2 * j2 + 1] * w.y;
        }
        a = fminf(fmaxf(a, 0.f), 1.f);
        part += a * Wo[oi];
    }
    part += __shfl_xor(part, 1);
    part += __shfl_xor(part, 2);
    part += __shfl_xor(part, 4);
    if (sub == 0) out[row] = part + bo[bkt] + l1c15 + l1f15;
}

extern "C" void kernel_launch(void* const* d_in, const int* in_sizes, int n_in,
                              void* d_out, int out_size, void* d_ws, size_t ws_size,
                              hipStream_t stream) {
    const float* x   = (const float*)d_in[0];
    const int*   idx = (const int*)  d_in[1];
    const float* W1  = (const float*)d_in[2];
    const float* b1  = (const float*)d_in[3];
    const float* Wf  = (const float*)d_in[4];
    const float* bf  = (const float*)d_in[5];
    const float* W2  = (const float*)d_in[6];
    const float* b2  = (const float*)d_in[7];
    const float* Wo  = (const float*)d_in[8];
    const float* bo  = (const float*)d_in[9];
    float* out = (float*)d_out;

    // ws layout: pt (3*16384*32*4 = 6291456 B) | pw (442368 B)  => 6.73 MB
    float* pt = (float*)d_ws;
    bf16*  pw = (bf16*)((char*)d_ws + (size_t)NSPLIT * ROWS * PCOLS * 4);

    pack_weights<<<dim3((NOUT * 192 + 255) / 256), dim3(256), 0, stream>>>(W1, Wf, pw);
    gemm_l1<<<dim3(NSPLIT * BLKS), dim3(512), 0, stream>>>(x, idx, pw, pt);
    epilogue<<<dim3(ROWS / 32), dim3(256), 0, stream>>>(pt, idx, b1, bf, W2, b2, Wo, bo, out);
}